// Round 3
// baseline (196.351 us; speedup 1.0000x reference)
//
#include <hip/hip_runtime.h>
#include <hip/hip_bf16.h>
#include <math.h>
#include <stdint.h>
#include <string.h>

#define TSEQ 2048
#define DMODEL 1024
#define NH 16
#define HD 64
#define BROWS 4096   // b*t
#define BH 32        // b*h

typedef __attribute__((ext_vector_type(8))) short short8;
typedef __attribute__((ext_vector_type(4))) float floatx4;

#define MFMA16 __builtin_amdgcn_mfma_f32_16x16x32_bf16
// 3-bit chunk-XOR swizzle on 64-short (128 B) rows
#define SWZ8(r, q) ((((q) ^ ((r) & 7)) * 8))

#define QSCALE 0.18033688011112042f   // 0.125 * log2(e); p = exp2(s) = exp(s/log2e)

__device__ __forceinline__ unsigned short bf16_rne(float f) {
    uint32_t u = __float_as_uint(f);
    u += 0x7FFFu + ((u >> 16) & 1u);
    return (unsigned short)(u >> 16);
}

__device__ __forceinline__ uint32_t pack_bf16x2(float a, float b) {
    __hip_bfloat162 h = __float22bfloat162_rn(float2{a, b});
    uint32_t r;
    memcpy(&r, &h, 4);
    return r;
}

__device__ __forceinline__ void split_bf16(float f, short& hi, short& lo) {
    uint32_t u = __float_as_uint(f);
    hi = (short)(u >> 16);
    float hif = __uint_as_float(u & 0xFFFF0000u);
    lo = (short)bf16_rne(f - hif);
}

__device__ __forceinline__ void async16(const void* g, void* l) {
    __builtin_amdgcn_global_load_lds(
        (__attribute__((address_space(1))) const uint32_t*)g,
        (__attribute__((address_space(3))) uint32_t*)l, 16, 0, 0);
}

// ---------------------------------------------------------------------------
// Fused pack (unchanged)
// ---------------------------------------------------------------------------
struct PackArgs {
    const float4* x;
    ushort4* xb;
    const float4* w[3];   // Wq, Wk, Wv
    ushort4* wb[3];
    const float4* wo;
    ushort4* woh;
    ushort4* wol;
};
__global__ __launch_bounds__(256) void pack_all(PackArgs a) {
    const int y = blockIdx.y;
    const int base = blockIdx.x * 256 + threadIdx.x;
    if (y == 0) {
#pragma unroll
        for (int it = 0; it < 4; ++it) {
            int i = base + it * 262144;
            float4 f = a.x[i];
            a.xb[i] = make_ushort4(bf16_rne(f.x), bf16_rne(f.y),
                                   bf16_rne(f.z), bf16_rne(f.w));
        }
    } else if (y <= 3) {
        int w = y - 1;
        float4 f = a.w[w][base];
        a.wb[w][base] = make_ushort4(bf16_rne(f.x), bf16_rne(f.y),
                                     bf16_rne(f.z), bf16_rne(f.w));
    } else {
        float4 f = a.wo[base];
        short h0, l0, h1, l1, h2, l2, h3, l3;
        split_bf16(f.x, h0, l0); split_bf16(f.y, h1, l1);
        split_bf16(f.z, h2, l2); split_bf16(f.w, h3, l3);
        a.woh[base] = make_ushort4(h0, h1, h2, h3);
        a.wol[base] = make_ushort4(l0, l1, l2, l3);
    }
}

// ---------------------------------------------------------------------------
// Fused QKV single-bf16 GEMM. 128x128, BK=64, 768 blocks. (unchanged)
// ---------------------------------------------------------------------------
__global__ __launch_bounds__(256) void gemm_qkv(
    const short* __restrict__ Xb,
    const short* __restrict__ Bq, const short* __restrict__ Bk,
    const short* __restrict__ Bv,
    short* __restrict__ Qo, short* __restrict__ Ko, short* __restrict__ Vo) {
    __shared__ short sA[128 * 64];
    __shared__ short sB[128 * 64];
    const int K = DMODEL;

    const int tid = threadIdx.x;
    const int lane = tid & 63, wave = tid >> 6;
    const int quad = lane >> 4, col = lane & 15;
    const int m0 = blockIdx.y * 128, n0 = blockIdx.x * 128;
    const int which = n0 >> 10;
    const int nn0 = n0 & 1023;
    const int wm = wave >> 1, wn = wave & 1;

    const short* B = (which == 0) ? Bq : (which == 1) ? Bk : Bv;
    const short* Asrc = Xb + (size_t)m0 * K;
    const short* Bsrc = B + (size_t)nn0 * K;

    const int srow = lane >> 3;
    const int soff = (((lane & 7) ^ srow) * 8);

    floatx4 acc[4][4] = {};

    for (int k0 = 0; k0 < K; k0 += 64) {
        __syncthreads();
#pragma unroll
        for (int j = 0; j < 8; ++j) {
            int idx = wave * 8 + j;
            int sub = idx & 15;
            const short* s = (idx < 16) ? Asrc : Bsrc;
            short* d = (idx < 16) ? sA : sB;
            async16(s + (size_t)(sub * 8 + srow) * K + k0 + soff, d + sub * 512);
        }
        __syncthreads();

#pragma unroll
        for (int s2 = 0; s2 < 2; ++s2) {
            short8 a_b[4], b_b[4];
#pragma unroll
            for (int mi = 0; mi < 4; ++mi) {
                int r = wm * 64 + mi * 16 + col;
                a_b[mi] = *(const short8*)&sA[r * 64 + SWZ8(r, s2 * 4 + quad)];
            }
#pragma unroll
            for (int ni = 0; ni < 4; ++ni) {
                int r = wn * 64 + ni * 16 + col;
                b_b[ni] = *(const short8*)&sB[r * 64 + SWZ8(r, s2 * 4 + quad)];
            }
            if (which == 2) {
#pragma unroll
                for (int mi = 0; mi < 4; ++mi)
#pragma unroll
                    for (int ni = 0; ni < 4; ++ni)
                        acc[mi][ni] = MFMA16(a_b[mi], b_b[ni], acc[mi][ni], 0, 0, 0);
            } else {
#pragma unroll
                for (int mi = 0; mi < 4; ++mi)
#pragma unroll
                    for (int ni = 0; ni < 4; ++ni)
                        acc[mi][ni] = MFMA16(b_b[ni], a_b[mi], acc[mi][ni], 0, 0, 0);
            }
        }
    }

    const int mb = m0 + wm * 64;
    const int nlb = nn0 + wn * 64;
    if (which == 2) {
        // V^T [bh][hd][t], kappa-permuted window position + chunk-XOR swizzle
#pragma unroll
        for (int ni = 0; ni < 4; ++ni) {
            int n = nlb + ni * 16 + col;
            int h = n >> 6, hd = n & 63;
#pragma unroll
            for (int mi = 0; mi < 4; ++mi) {
                int m4 = mb + mi * 16 + quad * 4;
                int b = m4 >> 11, t0 = m4 & 2047;
                // kappa^-1: key bits [t5][t4][t3t2][t1t0] -> s = [t5][t3t2][t4][t1t0]
                int sw = (t0 & 32) | ((t0 & 12) << 1) | ((t0 & 16) >> 2);
                int tsw = (t0 & ~63) | ((((sw >> 3) ^ (hd & 7)) << 3) | (sw & 7));
                size_t row = ((size_t)(b * NH + h) * HD + hd) * TSEQ;
                *(ushort4*)&Vo[row + tsw] =
                    make_ushort4(bf16_rne(acc[mi][ni][0]), bf16_rne(acc[mi][ni][1]),
                                 bf16_rne(acc[mi][ni][2]), bf16_rne(acc[mi][ni][3]));
            }
        }
    } else {
        short* O = (which == 0) ? Qo : Ko;
        const float sc = (which == 0) ? QSCALE : 1.0f;
#pragma unroll
        for (int mi = 0; mi < 4; ++mi) {
            int m = mb + mi * 16 + col;
            int b = m >> 11, t = m & 2047;
#pragma unroll
            for (int ni = 0; ni < 4; ++ni) {
                int n = nlb + ni * 16 + quad * 4;
                int h = n >> 6, hd = n & 63;
                int hds = (which == 1) ? ((((hd >> 3) ^ (t & 7)) << 3) | (hd & 7)) : hd;
                size_t idx = ((size_t)(b * NH + h) * TSEQ + t) * HD + hds;
                *(ushort4*)&O[idx] =
                    make_ushort4(bf16_rne(acc[mi][ni][0] * sc), bf16_rne(acc[mi][ni][1] * sc),
                                 bf16_rne(acc[mi][ni][2] * sc), bf16_rne(acc[mi][ni][3] * sc));
            }
        }
    }
}

// ---------------------------------------------------------------------------
// Flash attention. R2: __launch_bounds__(512,4) -> 128 VGPR budget (occupancy
// is LDS-limited to 2 blocks/CU = 4 waves/SIMD anyway; R1's 52-VGPR alloc was
// causing register juggling = the anomalous VALUBusy). kt-loop unrolled x2 so
// the dbuf index is compile-time; all K/V fragment ds_reads become 4 base
// pointers + compile-time immediate offsets (chunk-XOR depends only on
// col&7/quad/c); staging uses 4 pointers advanced by a constant stride.
// ---------------------------------------------------------------------------
#define ATTN_COMPUTE(DB)                                                        \
    {                                                                           \
        _Pragma("unroll")                                                       \
        for (int u = 0; u < 2; ++u) {                                           \
            floatx4 s[4] = {};                                                  \
            __builtin_amdgcn_s_setprio(1);                                      \
            _Pragma("unroll")                                                   \
            for (int k4 = 0; k4 < 4; ++k4) {                                    \
                short8 kf0 = *(const short8*)(kb0 + (DB) * 8192 + u * 4096 + k4 * 1024); \
                short8 kf1 = *(const short8*)(kb1 + (DB) * 8192 + u * 4096 + k4 * 1024); \
                s[k4] = MFMA16(kf0, qf[0], s[k4], 0, 0, 0);                     \
                s[k4] = MFMA16(kf1, qf[1], s[k4], 0, 0, 0);                     \
            }                                                                   \
            __builtin_amdgcn_s_setprio(0);                                      \
            float p[4][4];                                                      \
            _Pragma("unroll")                                                   \
            for (int k4 = 0; k4 < 4; ++k4)                                      \
                _Pragma("unroll")                                               \
                for (int r4 = 0; r4 < 4; ++r4)                                  \
                    p[k4][r4] = __builtin_amdgcn_exp2f(s[k4][r4]);              \
            _Pragma("unroll")                                                   \
            for (int c = 0; c < 2; ++c) {                                       \
                union { short8 v; uint32_t w[4]; } pf;                          \
                pf.w[0] = pack_bf16x2(p[2 * c][0], p[2 * c][1]);                \
                pf.w[1] = pack_bf16x2(p[2 * c][2], p[2 * c][3]);                \
                pf.w[2] = pack_bf16x2(p[2 * c + 1][0], p[2 * c + 1][1]);        \
                pf.w[3] = pack_bf16x2(p[2 * c + 1][2], p[2 * c + 1][3]);        \
                const short* vbc = c ? vb1 : vb0;                               \
                __builtin_amdgcn_s_setprio(1);                                  \
                lacc = MFMA16(ones.v, pf.v, lacc, 0, 0, 0);                     \
                _Pragma("unroll")                                               \
                for (int ni = 0; ni < 4; ++ni) {                                \
                    short8 vf = *(const short8*)(vbc + (DB) * 8192 + u * 4096 + ni * 1024); \
                    O[ni] = MFMA16(vf, pf.v, O[ni], 0, 0, 0);                   \
                }                                                               \
                __builtin_amdgcn_s_setprio(0);                                  \
            }                                                                   \
        }                                                                       \
    }

#define STAGE(LB)                                                               \
    {                                                                           \
        async16(g0, (LB) + 0 * 512);                                            \
        async16(g1, (LB) + 1 * 512);                                            \
        async16(g2, (LB) + 2 * 512);                                            \
        async16(g3, (LB) + 3 * 512);                                            \
        g0 += ktstep; g1 += ktstep; g2 += ktstep; g3 += ktstep;                 \
    }

__global__ __launch_bounds__(512, 4) void attn_bf16(
    const short* __restrict__ Qb, const short* __restrict__ Kb,
    const short* __restrict__ Vb, short* __restrict__ Cb) {
    __shared__ short sK[2][2][64 * 64];   // [dbuf][tile]
    __shared__ short sV[2][2][64 * 64];

    const int tid = threadIdx.x;
    const int lane = tid & 63, wave = tid >> 6;
    const int quad = lane >> 4, col = lane & 15;
    const int qt = blockIdx.x, bh = blockIdx.y;
    const size_t bhoff = (size_t)bh * TSEQ * HD;

    // Q as B-operand frags: B[n=q=col][k=quad*8+j]
    const size_t qrow = (size_t)(qt * 128 + wave * 16 + col) * HD;
    short8 qf[2];
#pragma unroll
    for (int c = 0; c < 2; ++c)
        qf[c] = *(const short8*)&Qb[bhoff + qrow + c * 32 + quad * 8];

    const int srow = lane >> 3;
    const int schunk = (lane & 7) * 8;   // K/V globally pre-swizzled

    // staging geometry: wave w stages 4 slots n = w*4 + j
    //   waves 0-3: K, waves 4-7: V;  tile = (wave>>1)&1;  sub = (wave&1)*4 + j
    const int isV = wave >> 2;
    const int tl = (wave >> 1) & 1;
    const int sb = (wave & 1) * 4;

    const short *g0, *g1, *g2, *g3;
    size_t ktstep;
    if (!isV) {
        g0 = Kb + bhoff + (size_t)(tl * 64 + (sb + 0) * 8 + srow) * HD + schunk;
        g1 = Kb + bhoff + (size_t)(tl * 64 + (sb + 1) * 8 + srow) * HD + schunk;
        g2 = Kb + bhoff + (size_t)(tl * 64 + (sb + 2) * 8 + srow) * HD + schunk;
        g3 = Kb + bhoff + (size_t)(tl * 64 + (sb + 3) * 8 + srow) * HD + schunk;
        ktstep = (size_t)128 * HD;
    } else {
        g0 = Vb + bhoff + (size_t)((sb + 0) * 8 + srow) * TSEQ + tl * 64 + schunk;
        g1 = Vb + bhoff + (size_t)((sb + 1) * 8 + srow) * TSEQ + tl * 64 + schunk;
        g2 = Vb + bhoff + (size_t)((sb + 2) * 8 + srow) * TSEQ + tl * 64 + schunk;
        g3 = Vb + bhoff + (size_t)((sb + 3) * 8 + srow) * TSEQ + tl * 64 + schunk;
        ktstep = 128;
    }
    short* lb0_ = isV ? &sV[0][tl][sb * 512] : &sK[0][tl][sb * 512];
    short* lb1_ = isV ? &sV[1][tl][sb * 512] : &sK[1][tl][sb * 512];

    // LDS fragment-read bases: all ds_reads are base + compile-time imm.
    // K frag (c, k4): addr = kb_c + DB*8192 + u*4096 + k4*1024   (shorts)
    // V frag (c, ni): addr = vb_c + DB*8192 + u*4096 + ni*1024
    const int ch0 = ((quad ^ (col & 7)) << 3);
    const int ch1 = (((4 + quad) ^ (col & 7)) << 3);
    const short* kb0 = &sK[0][0][col * 64 + ch0];
    const short* kb1 = &sK[0][0][col * 64 + ch1];
    const short* vb0 = &sV[0][0][col * 64 + ch0];
    const short* vb1 = &sV[0][0][col * 64 + ch1];

    // bf16 1.0 x8 for the l-accumulating MFMA
    union { short8 v; short s[8]; } ones;
#pragma unroll
    for (int j = 0; j < 8; ++j) ones.s[j] = (short)0x3F80;

    floatx4 lacc = {};      // every element = running l for q = col
    floatx4 O[4] = {};      // O^T: hd = ni*16 + quad*4 + r, q = col

    STAGE(lb0_);            // tile 0 -> db0

    for (int kt2 = 0; kt2 < 8; ++kt2) {
        // even tile (db0): prefetch odd tile into db1
        STAGE(lb1_);
        asm volatile("s_waitcnt vmcnt(4)" ::: "memory");
        __builtin_amdgcn_s_barrier();
        ATTN_COMPUTE(0);
        __builtin_amdgcn_s_barrier();

        // odd tile (db1): prefetch next even tile into db0
        if (kt2 < 7) {
            STAGE(lb0_);
            asm volatile("s_waitcnt vmcnt(4)" ::: "memory");
        } else {
            asm volatile("s_waitcnt vmcnt(0)" ::: "memory");
        }
        __builtin_amdgcn_s_barrier();
        ATTN_COMPUTE(1);
        __builtin_amdgcn_s_barrier();
    }

    // l is fully summed over all keys by the ones-MFMA (B-layout spans k=0..31)
    const float inv = 1.0f / lacc[0];

    const int b = bh >> 4, h = bh & 15;
    const int trow = qt * 128 + wave * 16 + col;
    const size_t obase = (size_t)(b * TSEQ + trow) * DMODEL + h * 64;
#pragma unroll
    for (int ni = 0; ni < 4; ++ni) {
        uint2 pk;
        pk.x = pack_bf16x2(O[ni][0] * inv, O[ni][1] * inv);
        pk.y = pack_bf16x2(O[ni][2] * inv, O[ni][3] * inv);
        *(uint2*)&Cb[obase + ni * 16 + quad * 4] = pk;
    }
}

// ---------------------------------------------------------------------------
// Out-proj 2-term, operand-flipped (unchanged). 128x64, BK=64.
// ---------------------------------------------------------------------------
__global__ __launch_bounds__(256) void gemm_out(
    const short* __restrict__ Ab,
    const short* __restrict__ Bh, const short* __restrict__ Bl,
    const float* __restrict__ bias, float* __restrict__ Of) {
    __shared__ short sA[128 * 64];
    __shared__ short sBh[64 * 64];
    __shared__ short sBl[64 * 64];
    const int K = DMODEL, N = DMODEL;

    const int tid = threadIdx.x;
    const int lane = tid & 63, wave = tid >> 6;
    const int quad = lane >> 4, col = lane & 15;
    const int m0 = blockIdx.y * 128, n0 = blockIdx.x * 64;
    const int wm = wave >> 1, wn = wave & 1;

    const short* Asrc = Ab + (size_t)m0 * K;
    const short* Bhsrc = Bh + (size_t)n0 * K;
    const short* Blsrc = Bl + (size_t)n0 * K;
    const int srow = lane >> 3;
    const int soff = (((lane & 7) ^ srow) * 8);

    floatx4 acc[4][2] = {};

    for (int k0 = 0; k0 < K; k0 += 64) {
        __syncthreads();
#pragma unroll
        for (int j = 0; j < 8; ++j) {
            int idx = wave * 8 + j;
            int buf = (idx < 16) ? 0 : (idx < 24) ? 1 : 2;
            int sub = (buf == 0) ? idx : (buf == 1) ? idx - 16 : idx - 24;
            const short* s = (buf == 0) ? Asrc : (buf == 1) ? Bhsrc : Blsrc;
            short* d = (buf == 0) ? sA : (buf == 1) ? sBh : sBl;
            async16(s + (size_t)(sub * 8 + srow) * K + k0 + soff, d + sub * 512);
        }
        __syncthreads();

#pragma unroll
        for (int s2 = 0; s2 < 2; ++s2) {
            short8 a_b[4], b_h[2], b_l[2];
#pragma unroll
            for (int mi = 0; mi < 4; ++mi) {
                int r = wm * 64 + mi * 16 + col;
                a_b[mi] = *(const short8*)&sA[r * 64 + SWZ8(r, s2 * 4 + quad)];
            }
#pragma unroll
            for (int ni = 0; ni < 2; ++ni) {
                int r = wn * 32 + ni * 16 + col;
                b_h[ni] = *(const short8*)&sBh[r * 64 + SWZ8(r, s2 * 4 + quad)];
                b_l[ni] = *(const short8*)&sBl[r * 64 + SWZ8(r, s2 * 4 + quad)];
            }
#pragma unroll
            for (int mi = 0; mi < 4; ++mi)
#pragma unroll
                for (int ni = 0; ni < 2; ++ni) {
                    acc[mi][ni] = MFMA16(b_h[ni], a_b[mi], acc[mi][ni], 0, 0, 0);
                    acc[mi][ni] = MFMA16(b_l[ni], a_b[mi], acc[mi][ni], 0, 0, 0);
                }
        }
    }

    const int mb = m0 + wm * 64, nb = n0 + wn * 32;
#pragma unroll
    for (int mi = 0; mi < 4; ++mi) {
        int m = mb + mi * 16 + col;
#pragma unroll
        for (int ni = 0; ni < 2; ++ni) {
            int n = nb + ni * 16 + quad * 4;
            float4 bv = *(const float4*)&bias[n];
            float4 o = make_float4(acc[mi][ni][0] + bv.x, acc[mi][ni][1] + bv.y,
                                   acc[mi][ni][2] + bv.z, acc[mi][ni][3] + bv.w);
            *(float4*)&Of[(size_t)m * N + n] = o;
        }
    }
}

// ---------------------------------------------------------------------------
extern "C" void kernel_launch(void* const* d_in, const int* in_sizes, int n_in,
                              void* d_out, int out_size, void* d_ws, size_t ws_size,
                              hipStream_t stream) {
    const float* x  = (const float*)d_in[0];
    const float* Wq = (const float*)d_in[1];
    const float* Wk = (const float*)d_in[2];
    const float* Wv = (const float*)d_in[3];
    const float* Wo = (const float*)d_in[4];
    const float* bo = (const float*)d_in[5];
    float* out = (float*)d_out;

    const size_t NX = (size_t)BROWS * DMODEL;   // 4M
    const size_t NW = (size_t)DMODEL * DMODEL;  // 1M
    short* p = (short*)d_ws;
    short *xb = p;
    short *wqb = xb + NX;
    short *wkb = wqb + NW;
    short *wvb = wkb + NW;
    short *woh = wvb + NW; short *wol = woh + NW;
    short *qb = wol + NW;
    short *kb = qb + NX;
    short *vb = kb + NX;
    short *cb = vb + NX;

    PackArgs pa;
    pa.x = (const float4*)x; pa.xb = (ushort4*)xb;
    pa.w[0] = (const float4*)Wq; pa.wb[0] = (ushort4*)wqb;
    pa.w[1] = (const float4*)Wk; pa.wb[1] = (ushort4*)wkb;
    pa.w[2] = (const float4*)Wv; pa.wb[2] = (ushort4*)wvb;
    pa.wo = (const float4*)Wo; pa.woh = (ushort4*)woh; pa.wol = (ushort4*)wol;
    pack_all<<<dim3(1024, 5), dim3(256), 0, stream>>>(pa);

    gemm_qkv<<<dim3(3 * DMODEL / 128, BROWS / 128), dim3(256), 0, stream>>>(
        xb, wqb, wkb, wvb, qb, kb, vb);

    attn_bf16<<<dim3(TSEQ / 128, BH), dim3(512), 0, stream>>>(qb, kb, vb, cb);

    gemm_out<<<dim3(DMODEL / 64, BROWS / 128), dim3(256), 0, stream>>>(cb, woh, wol, bo, out);
}

// Round 4
// 192.830 us; speedup vs baseline: 1.0183x; 1.0183x over previous
//
#include <hip/hip_runtime.h>
#include <hip/hip_bf16.h>
#include <math.h>
#include <stdint.h>
#include <string.h>

#define TSEQ 2048
#define DMODEL 1024
#define NH 16
#define HD 64
#define BROWS 4096   // b*t
#define BH 32        // b*h

typedef __attribute__((ext_vector_type(8))) short short8;
typedef __attribute__((ext_vector_type(4))) float floatx4;
typedef __attribute__((ext_vector_type(16))) float floatx16;

#define MFMA16 __builtin_amdgcn_mfma_f32_16x16x32_bf16
#define MFMA32 __builtin_amdgcn_mfma_f32_32x32x16_bf16
// 3-bit chunk-XOR swizzle on 64-short (128 B) rows
#define SWZ8(r, q) ((((q) ^ ((r) & 7)) * 8))

#define QSCALE 0.18033688011112042f   // 0.125 * log2(e); p = exp2(s) = exp(s/log2e)

__device__ __forceinline__ unsigned short bf16_rne(float f) {
    uint32_t u = __float_as_uint(f);
    u += 0x7FFFu + ((u >> 16) & 1u);
    return (unsigned short)(u >> 16);
}

__device__ __forceinline__ uint32_t pack_bf16x2(float a, float b) {
    __hip_bfloat162 h = __float22bfloat162_rn(float2{a, b});
    uint32_t r;
    memcpy(&r, &h, 4);
    return r;
}

__device__ __forceinline__ void split_bf16(float f, short& hi, short& lo) {
    uint32_t u = __float_as_uint(f);
    hi = (short)(u >> 16);
    float hif = __uint_as_float(u & 0xFFFF0000u);
    lo = (short)bf16_rne(f - hif);
}

__device__ __forceinline__ void async16(const void* g, void* l) {
    __builtin_amdgcn_global_load_lds(
        (__attribute__((address_space(1))) const uint32_t*)g,
        (__attribute__((address_space(3))) uint32_t*)l, 16, 0, 0);
}

// ---------------------------------------------------------------------------
// Fused pack (unchanged)
// ---------------------------------------------------------------------------
struct PackArgs {
    const float4* x;
    ushort4* xb;
    const float4* w[3];   // Wq, Wk, Wv
    ushort4* wb[3];
    const float4* wo;
    ushort4* woh;
    ushort4* wol;
};
__global__ __launch_bounds__(256) void pack_all(PackArgs a) {
    const int y = blockIdx.y;
    const int base = blockIdx.x * 256 + threadIdx.x;
    if (y == 0) {
#pragma unroll
        for (int it = 0; it < 4; ++it) {
            int i = base + it * 262144;
            float4 f = a.x[i];
            a.xb[i] = make_ushort4(bf16_rne(f.x), bf16_rne(f.y),
                                   bf16_rne(f.z), bf16_rne(f.w));
        }
    } else if (y <= 3) {
        int w = y - 1;
        float4 f = a.w[w][base];
        a.wb[w][base] = make_ushort4(bf16_rne(f.x), bf16_rne(f.y),
                                     bf16_rne(f.z), bf16_rne(f.w));
    } else {
        float4 f = a.wo[base];
        short h0, l0, h1, l1, h2, l2, h3, l3;
        split_bf16(f.x, h0, l0); split_bf16(f.y, h1, l1);
        split_bf16(f.z, h2, l2); split_bf16(f.w, h3, l3);
        a.woh[base] = make_ushort4(h0, h1, h2, h3);
        a.wol[base] = make_ushort4(l0, l1, l2, l3);
    }
}

// ---------------------------------------------------------------------------
// Fused QKV single-bf16 GEMM. 128x128, BK=64, 768 blocks.
// V: [bh][hd][t]; within-64-window key positions now permuted by sigma =
//    swap(bit2,bit3) (self-inverse) so attn's 32x32 PV B-operand is regs
//    8c..8c+7 of the QK accumulator directly; then chunk-XOR by hd&7.
// ---------------------------------------------------------------------------
__global__ __launch_bounds__(256) void gemm_qkv(
    const short* __restrict__ Xb,
    const short* __restrict__ Bq, const short* __restrict__ Bk,
    const short* __restrict__ Bv,
    short* __restrict__ Qo, short* __restrict__ Ko, short* __restrict__ Vo) {
    __shared__ short sA[128 * 64];
    __shared__ short sB[128 * 64];
    const int K = DMODEL;

    const int tid = threadIdx.x;
    const int lane = tid & 63, wave = tid >> 6;
    const int quad = lane >> 4, col = lane & 15;
    const int m0 = blockIdx.y * 128, n0 = blockIdx.x * 128;
    const int which = n0 >> 10;
    const int nn0 = n0 & 1023;
    const int wm = wave >> 1, wn = wave & 1;

    const short* B = (which == 0) ? Bq : (which == 1) ? Bk : Bv;
    const short* Asrc = Xb + (size_t)m0 * K;
    const short* Bsrc = B + (size_t)nn0 * K;

    const int srow = lane >> 3;
    const int soff = (((lane & 7) ^ srow) * 8);

    floatx4 acc[4][4] = {};

    for (int k0 = 0; k0 < K; k0 += 64) {
        __syncthreads();
#pragma unroll
        for (int j = 0; j < 8; ++j) {
            int idx = wave * 8 + j;
            int sub = idx & 15;
            const short* s = (idx < 16) ? Asrc : Bsrc;
            short* d = (idx < 16) ? sA : sB;
            async16(s + (size_t)(sub * 8 + srow) * K + k0 + soff, d + sub * 512);
        }
        __syncthreads();

#pragma unroll
        for (int s2 = 0; s2 < 2; ++s2) {
            short8 a_b[4], b_b[4];
#pragma unroll
            for (int mi = 0; mi < 4; ++mi) {
                int r = wm * 64 + mi * 16 + col;
                a_b[mi] = *(const short8*)&sA[r * 64 + SWZ8(r, s2 * 4 + quad)];
            }
#pragma unroll
            for (int ni = 0; ni < 4; ++ni) {
                int r = wn * 64 + ni * 16 + col;
                b_b[ni] = *(const short8*)&sB[r * 64 + SWZ8(r, s2 * 4 + quad)];
            }
            if (which == 2) {
#pragma unroll
                for (int mi = 0; mi < 4; ++mi)
#pragma unroll
                    for (int ni = 0; ni < 4; ++ni)
                        acc[mi][ni] = MFMA16(a_b[mi], b_b[ni], acc[mi][ni], 0, 0, 0);
            } else {
#pragma unroll
                for (int mi = 0; mi < 4; ++mi)
#pragma unroll
                    for (int ni = 0; ni < 4; ++ni)
                        acc[mi][ni] = MFMA16(b_b[ni], a_b[mi], acc[mi][ni], 0, 0, 0);
            }
        }
    }

    const int mb = m0 + wm * 64;
    const int nlb = nn0 + wn * 64;
    if (which == 2) {
        // V^T [bh][hd][t], sigma = swap(bit2,bit3) of local key + chunk-XOR
#pragma unroll
        for (int ni = 0; ni < 4; ++ni) {
            int n = nlb + ni * 16 + col;
            int h = n >> 6, hd = n & 63;
#pragma unroll
            for (int mi = 0; mi < 4; ++mi) {
                int m4 = mb + mi * 16 + quad * 4;
                int b = m4 >> 11, t0 = m4 & 2047;
                // sigma: swap bits 2 and 3 of the key index (involution)
                int sw = (t0 & 0x33) | ((t0 & 4) << 1) | ((t0 & 8) >> 1);
                int tsw = (t0 & ~63) | ((((sw >> 3) ^ (hd & 7)) << 3) | (sw & 7));
                size_t row = ((size_t)(b * NH + h) * HD + hd) * TSEQ;
                *(ushort4*)&Vo[row + tsw] =
                    make_ushort4(bf16_rne(acc[mi][ni][0]), bf16_rne(acc[mi][ni][1]),
                                 bf16_rne(acc[mi][ni][2]), bf16_rne(acc[mi][ni][3]));
            }
        }
    } else {
        short* O = (which == 0) ? Qo : Ko;
        const float sc = (which == 0) ? QSCALE : 1.0f;
#pragma unroll
        for (int mi = 0; mi < 4; ++mi) {
            int m = mb + mi * 16 + col;
            int b = m >> 11, t = m & 2047;
#pragma unroll
            for (int ni = 0; ni < 4; ++ni) {
                int n = nlb + ni * 16 + quad * 4;
                int h = n >> 6, hd = n & 63;
                int hds = (which == 1) ? ((((hd >> 3) ^ (t & 7)) << 3) | (hd & 7)) : hd;
                size_t idx = ((size_t)(b * NH + h) * TSEQ + t) * HD + hds;
                *(ushort4*)&O[idx] =
                    make_ushort4(bf16_rne(acc[mi][ni][0] * sc), bf16_rne(acc[mi][ni][1] * sc),
                                 bf16_rne(acc[mi][ni][2] * sc), bf16_rne(acc[mi][ni][3] * sc));
            }
        }
    }
}

// ---------------------------------------------------------------------------
// Flash attention, 32x32 MFMA form. 256 thr = 4 waves, 32 q/wave, 128 keys/kt.
// R3 theory: old 16x16 form was LDS-BW-bound (512 KB/kt/CU = 81% of LDS
// bandwidth). 32x32x16 doubles FLOP per operand byte -> 256 KB/kt/CU.
// S = MFMA32(K, Q): D[key=row][q=col]; lane (q=lane&31, hh=lane>>5) holds
// s[m][r] at key 32m + (r&3) + 8(r>>2) + 4hh.
// V stored sigma-permuted (swap bits 2,3) -> PV B-frag for MFMA t=2m+c is
// exactly p-regs 8c..8c+7 of chunk m: zero P LDS traffic, no lane exchange.
// O = MFMA32(V^T, P): D[hd=row][q=col], 2 accumulators (mi=0,1).
// l accumulated on VALU (4 chains), freeing the MFMA pipe.
// ---------------------------------------------------------------------------
#define ATTN_COMPUTE(DB)                                                        \
    {                                                                           \
        floatx16 s[4] = {};                                                     \
        __builtin_amdgcn_s_setprio(1);                                          \
        _Pragma("unroll")                                                       \
        for (int u = 0; u < 2; ++u)                                             \
            _Pragma("unroll")                                                   \
            for (int mm = 0; mm < 2; ++mm)                                      \
                _Pragma("unroll")                                               \
                for (int ks = 0; ks < 4; ++ks) {                                \
                    short8 kf = *(const short8*)(kB[ks] + (DB) * 8192 + u * 4096 + mm * 2048); \
                    s[u * 2 + mm] = MFMA32(kf, qf[ks], s[u * 2 + mm], 0, 0, 0); \
                }                                                               \
        __builtin_amdgcn_s_setprio(0);                                          \
        _Pragma("unroll")                                                       \
        for (int m = 0; m < 4; ++m) {                                           \
            float p[16];                                                        \
            _Pragma("unroll")                                                   \
            for (int r = 0; r < 16; ++r) {                                      \
                p[r] = __builtin_amdgcn_exp2f(s[m][r]);                         \
                lv[r & 3] += p[r];                                              \
            }                                                                   \
            _Pragma("unroll")                                                   \
            for (int c = 0; c < 2; ++c) {                                       \
                union { short8 v; uint32_t w[4]; } pf;                          \
                pf.w[0] = pack_bf16x2(p[8 * c + 0], p[8 * c + 1]);              \
                pf.w[1] = pack_bf16x2(p[8 * c + 2], p[8 * c + 3]);              \
                pf.w[2] = pack_bf16x2(p[8 * c + 4], p[8 * c + 5]);              \
                pf.w[3] = pack_bf16x2(p[8 * c + 6], p[8 * c + 7]);              \
                const int t = m * 2 + c, uu = t >> 2, tt = t & 3;               \
                __builtin_amdgcn_s_setprio(1);                                  \
                _Pragma("unroll")                                               \
                for (int mi = 0; mi < 2; ++mi) {                                \
                    short8 vf = *(const short8*)(vB[tt] + (DB) * 8192 + uu * 4096 + mi * 2048); \
                    O2[mi] = MFMA32(vf, pf.v, O2[mi], 0, 0, 0);                 \
                }                                                               \
                __builtin_amdgcn_s_setprio(0);                                  \
            }                                                                   \
        }                                                                       \
    }

#define STAGE(LB)                                                               \
    {                                                                           \
        _Pragma("unroll")                                                       \
        for (int j = 0; j < 8; ++j)                                             \
            async16(gb + (size_t)j * gstride, (LB) + j * 512);                  \
        gb += ktstep;                                                           \
    }

__global__ __launch_bounds__(256, 2) void attn_bf16(
    const short* __restrict__ Qb, const short* __restrict__ Kb,
    const short* __restrict__ Vb, short* __restrict__ Cb) {
    __shared__ short sK[2][2][64 * 64];   // [dbuf][tile64][key][hd-chunks]
    __shared__ short sV[2][2][64 * 64];   // [dbuf][tile64][hd][pos-chunks]

    const int tid = threadIdx.x;
    const int lane = tid & 63, wave = tid >> 6;      // wave 0..3
    const int q5 = lane & 31, hh = lane >> 5, l7 = lane & 7;
    const int qt = blockIdx.x, bh = blockIdx.y;
    const size_t bhoff = (size_t)bh * TSEQ * HD;

    // Q as B-operand frags: B[n=q=q5][k = hh*8+j + 16*ks]
    const size_t qrow = (size_t)(qt * 128 + wave * 32 + q5) * HD;
    short8 qf[4];
#pragma unroll
    for (int ks = 0; ks < 4; ++ks)
        qf[ks] = *(const short8*)&Qb[bhoff + qrow + ks * 16 + hh * 8];

    // staging: wave 0: K tile0, wave 1: K tile1, wave 2: V tile0, wave 3: V tile1
    const int srow = lane >> 3, schunk = (lane & 7) * 8;
    const int isV = wave >> 1, tl = wave & 1;
    const short* gb;
    size_t gstride, ktstep;
    if (!isV) {
        gb = Kb + bhoff + (size_t)(tl * 64 + srow) * HD + schunk;
        gstride = (size_t)8 * HD;
        ktstep = (size_t)128 * HD;
    } else {
        gb = Vb + bhoff + (size_t)srow * TSEQ + tl * 64 + schunk;
        gstride = (size_t)8 * TSEQ;
        ktstep = 128;
    }
    short* lb0 = isV ? sV[0][tl] : sK[0][tl];
    short* lb1 = isV ? sV[1][tl] : sK[1][tl];

    // LDS fragment-read bases: read = base + compile-time imm (db/u/mm in shorts)
    const short* kB[4];
    const short* vB[4];
#pragma unroll
    for (int w = 0; w < 4; ++w) {
        kB[w] = &sK[0][0][q5 * 64 + (((2 * w + hh) ^ l7) * 8)];
        vB[w] = &sV[0][0][q5 * 64 + (((2 * w + hh) ^ l7) * 8)];
    }

    floatx4 lv = {};        // 4-chain l accumulator, q = q5 (partial over hh)
    floatx16 O2[2] = {};    // O^T: hd = 32*mi + (r&3) + 8*(r>>2) + 4*hh, q = q5

    STAGE(lb0);             // tile 0 -> db0

    for (int kt2 = 0; kt2 < 8; ++kt2) {
        // even tile (db0): prefetch odd tile into db1
        STAGE(lb1);
        asm volatile("s_waitcnt vmcnt(8)" ::: "memory");
        __builtin_amdgcn_s_barrier();
        ATTN_COMPUTE(0);
        __builtin_amdgcn_s_barrier();

        // odd tile (db1): prefetch next even tile into db0
        if (kt2 < 7) {
            STAGE(lb0);
            asm volatile("s_waitcnt vmcnt(8)" ::: "memory");
        } else {
            asm volatile("s_waitcnt vmcnt(0)" ::: "memory");
        }
        __builtin_amdgcn_s_barrier();
        ATTN_COMPUTE(1);
        __builtin_amdgcn_s_barrier();
    }

    // l: this lane covers half the keys for q=q5; partner lane (hh^1) the rest
    float l_r = (lv[0] + lv[1]) + (lv[2] + lv[3]);
    l_r += __shfl_xor(l_r, 32);
    const float inv = 1.0f / l_r;

    const int b = bh >> 4, h = bh & 15;
    const int trow = qt * 128 + wave * 32 + q5;
    const size_t obase = (size_t)(b * TSEQ + trow) * DMODEL + h * 64;
#pragma unroll
    for (int mi = 0; mi < 2; ++mi)
#pragma unroll
        for (int g = 0; g < 4; ++g) {
            uint2 pk;
            pk.x = pack_bf16x2(O2[mi][4 * g + 0] * inv, O2[mi][4 * g + 1] * inv);
            pk.y = pack_bf16x2(O2[mi][4 * g + 2] * inv, O2[mi][4 * g + 3] * inv);
            *(uint2*)&Cb[obase + mi * 32 + g * 8 + hh * 4] = pk;
        }
}

// ---------------------------------------------------------------------------
// Out-proj 2-term, operand-flipped (unchanged). 128x64, BK=64.
// ---------------------------------------------------------------------------
__global__ __launch_bounds__(256) void gemm_out(
    const short* __restrict__ Ab,
    const short* __restrict__ Bh, const short* __restrict__ Bl,
    const float* __restrict__ bias, float* __restrict__ Of) {
    __shared__ short sA[128 * 64];
    __shared__ short sBh[64 * 64];
    __shared__ short sBl[64 * 64];
    const int K = DMODEL, N = DMODEL;

    const int tid = threadIdx.x;
    const int lane = tid & 63, wave = tid >> 6;
    const int quad = lane >> 4, col = lane & 15;
    const int m0 = blockIdx.y * 128, n0 = blockIdx.x * 64;
    const int wm = wave >> 1, wn = wave & 1;

    const short* Asrc = Ab + (size_t)m0 * K;
    const short* Bhsrc = Bh + (size_t)n0 * K;
    const short* Blsrc = Bl + (size_t)n0 * K;
    const int srow = lane >> 3;
    const int soff = (((lane & 7) ^ srow) * 8);

    floatx4 acc[4][2] = {};

    for (int k0 = 0; k0 < K; k0 += 64) {
        __syncthreads();
#pragma unroll
        for (int j = 0; j < 8; ++j) {
            int idx = wave * 8 + j;
            int buf = (idx < 16) ? 0 : (idx < 24) ? 1 : 2;
            int sub = (buf == 0) ? idx : (buf == 1) ? idx - 16 : idx - 24;
            const short* s = (buf == 0) ? Asrc : (buf == 1) ? Bhsrc : Blsrc;
            short* d = (buf == 0) ? sA : (buf == 1) ? sBh : sBl;
            async16(s + (size_t)(sub * 8 + srow) * K + k0 + soff, d + sub * 512);
        }
        __syncthreads();

#pragma unroll
        for (int s2 = 0; s2 < 2; ++s2) {
            short8 a_b[4], b_h[2], b_l[2];
#pragma unroll
            for (int mi = 0; mi < 4; ++mi) {
                int r = wm * 64 + mi * 16 + col;
                a_b[mi] = *(const short8*)&sA[r * 64 + SWZ8(r, s2 * 4 + quad)];
            }
#pragma unroll
            for (int ni = 0; ni < 2; ++ni) {
                int r = wn * 32 + ni * 16 + col;
                b_h[ni] = *(const short8*)&sBh[r * 64 + SWZ8(r, s2 * 4 + quad)];
                b_l[ni] = *(const short8*)&sBl[r * 64 + SWZ8(r, s2 * 4 + quad)];
            }
#pragma unroll
            for (int mi = 0; mi < 4; ++mi)
#pragma unroll
                for (int ni = 0; ni < 2; ++ni) {
                    acc[mi][ni] = MFMA16(b_h[ni], a_b[mi], acc[mi][ni], 0, 0, 0);
                    acc[mi][ni] = MFMA16(b_l[ni], a_b[mi], acc[mi][ni], 0, 0, 0);
                }
        }
    }

    const int mb = m0 + wm * 64, nb = n0 + wn * 32;
#pragma unroll
    for (int mi = 0; mi < 4; ++mi) {
        int m = mb + mi * 16 + col;
#pragma unroll
        for (int ni = 0; ni < 2; ++ni) {
            int n = nb + ni * 16 + quad * 4;
            float4 bv = *(const float4*)&bias[n];
            float4 o = make_float4(acc[mi][ni][0] + bv.x, acc[mi][ni][1] + bv.y,
                                   acc[mi][ni][2] + bv.z, acc[mi][ni][3] + bv.w);
            *(float4*)&Of[(size_t)m * N + n] = o;
        }
    }
}

// ---------------------------------------------------------------------------
extern "C" void kernel_launch(void* const* d_in, const int* in_sizes, int n_in,
                              void* d_out, int out_size, void* d_ws, size_t ws_size,
                              hipStream_t stream) {
    const float* x  = (const float*)d_in[0];
    const float* Wq = (const float*)d_in[1];
    const float* Wk = (const float*)d_in[2];
    const float* Wv = (const float*)d_in[3];
    const float* Wo = (const float*)d_in[4];
    const float* bo = (const float*)d_in[5];
    float* out = (float*)d_out;

    const size_t NX = (size_t)BROWS * DMODEL;   // 4M
    const size_t NW = (size_t)DMODEL * DMODEL;  // 1M
    short* p = (short*)d_ws;
    short *xb = p;
    short *wqb = xb + NX;
    short *wkb = wqb + NW;
    short *wvb = wkb + NW;
    short *woh = wvb + NW; short *wol = woh + NW;
    short *qb = wol + NW;
    short *kb = qb + NX;
    short *vb = kb + NX;
    short *cb = vb + NX;

    PackArgs pa;
    pa.x = (const float4*)x; pa.xb = (ushort4*)xb;
    pa.w[0] = (const float4*)Wq; pa.wb[0] = (ushort4*)wqb;
    pa.w[1] = (const float4*)Wk; pa.wb[1] = (ushort4*)wkb;
    pa.w[2] = (const float4*)Wv; pa.wb[2] = (ushort4*)wvb;
    pa.wo = (const float4*)Wo; pa.woh = (ushort4*)woh; pa.wol = (ushort4*)wol;
    pack_all<<<dim3(1024, 5), dim3(256), 0, stream>>>(pa);

    gemm_qkv<<<dim3(3 * DMODEL / 128, BROWS / 128), dim3(256), 0, stream>>>(
        xb, wqb, wkb, wvb, qb, kb, vb);

    attn_bf16<<<dim3(TSEQ / 128, BH), dim3(256), 0, stream>>>(qb, kb, vb, cb);

    gemm_out<<<dim3(DMODEL / 64, BROWS / 128), dim3(256), 0, stream>>>(cb, woh, wol, bo, out);
}